// Round 5
// baseline (3027.173 us; speedup 1.0000x reference)
//
#include <hip/hip_runtime.h>
#include <stdint.h>

// ---------------------------------------------------------------------------
// Persistent-kernel LSTM (relu g-gate, h = o*c, no tanh).
// B=128, S=1024, I=256, H=512, O=10.
//
// R12 = R11 byte-identical EXCEPT sync is a mailbox matrix:
//  * mbox[g][consumer][producer], one 64-B line each (512 KB total, 64 KB
//    per group -> L2-resident). Single-writer / single-poller per line.
//  * Producer slot p: after payload drain + B4, ONE 32-lane plain vector
//    store of (t+1) into mbox[g][0..31][p] (plain flag store = R7-proven).
//  * Consumer slot s: ONE 32-lane vector atomic (TCC global_atomic_add 0
//    sc0, proven fresh) over its own row mbox[g][s][0..31]; __all(v>=t).
//    Per-line queue depth <= 2 (was ~32) -> discovery ~= one L2 atomic
//    round trip instead of a serialized RMW queue rotation (~1000 cy).
//  * Everything else unchanged: LDS staging of payload, W=16
//    capacity-eviction freshness, B1/B2/B3/B4, x double-buffer pipeline.
// ---------------------------------------------------------------------------

#define GROUPS 8
#define BC     16
#define S_LEN  1024
#define I_DIM  256
#define H_DIM  512
#define NBLK   512
#define FSTRIDE 16                    // mailbox line stride in ints (64 B)
#define PAYG   (BC * H_DIM)           // 8192 shorts per group per slot
#define PAYSLOT (GROUPS * PAYG)       // shorts per rotation slot
#define MBOX_BYTES (GROUPS * 32 * 32 * FSTRIDE * 4)   // 512 KB
#define HPAY_OFF   (8192 + MBOX_BYTES)                // = 532480, 4K-aligned

typedef float f32x4 __attribute__((ext_vector_type(4)));
typedef short s16x8 __attribute__((ext_vector_type(8)));

__device__ __forceinline__ unsigned short f2bf(float f) {
  unsigned u = __float_as_uint(f);
  u += 0x7fffu + ((u >> 16) & 1u);   // RNE
  return (unsigned short)(u >> 16);
}
__device__ __forceinline__ float bf2f(unsigned short h) {
  return __uint_as_float(((unsigned)h) << 16);
}
__device__ __forceinline__ float sigf(float x) { return 1.0f / (1.0f + __expf(-x)); }

// TCC-executed read (atomic add 0, returns old): PROVEN fresh on gfx950.
__device__ __forceinline__ int poll_local(uint64_t a) {
  int v;
  asm volatile("global_atomic_add %0, %1, %2, off sc0\n\ts_waitcnt vmcnt(0)"
               : "=v"(v) : "v"(a), "v"(0) : "memory");
  return v;
}
__device__ __forceinline__ int ld_sc1(uint64_t a) {
  int v;
  asm volatile("global_load_dword %0, %1, off sc1\n\ts_waitcnt vmcnt(0)"
               : "=v"(v) : "v"(a) : "memory");
  return v;
}
__device__ __forceinline__ void st_sc1(uint64_t a, int v) {
  asm volatile("global_store_dword %0, %1, off sc1" :: "v"(a), "v"(v) : "memory");
}
__device__ __forceinline__ void st_flag(uint64_t a, int v) {
  asm volatile("global_store_dword %0, %1, off" :: "v"(a), "v"(v) : "memory");
}
__device__ __forceinline__ void drain_vm() {
  asm volatile("s_waitcnt vmcnt(0)" ::: "memory");
}

__global__ __launch_bounds__(256, 2)
void lstm_persistent(const float* __restrict__ x,
                     const float* __restrict__ Wih,
                     const float* __restrict__ Whh,
                     const float* __restrict__ bih,
                     const float* __restrict__ bhh,
                     const float* __restrict__ fcw,
                     const float* __restrict__ fcb,
                     float* __restrict__ out,
                     int* __restrict__ arrive,           // [1], zeroed
                     int* __restrict__ table,            // [NBLK]
                     int* __restrict__ flags,            // mailboxes, zeroed
                     unsigned short* __restrict__ hpay,  // [W][GROUPS][PAYG]
                     int wmask)
{
  __shared__ __align__(16) unsigned short x_s[2][8][512];  // fragment-order x
  __shared__ __align__(16) unsigned short h_stage[8192];   // one group-slot of h
  __shared__ __align__(16) float gates[4][BC][18];
  __shared__ int tbl[NBLK];
  __shared__ unsigned long long seen[GROUPS][4];
  __shared__ int s_grp, s_slot, s_abort;

  const int tid  = threadIdx.x;
  const int wave = tid >> 6;        // gate section 0..3 (i,f,g,o)
  const int lane = tid & 63;
  const int q    = lane >> 4;
  const int l15  = lane & 15;
  const int bid  = blockIdx.x;

  // ---- rendezvous: publish (xcd, cu-key), wait for all, elect workers ----
  const int xcd = __builtin_amdgcn_s_getreg((31u << 11) | 20) & 7;     // XCC_ID
  const int cuk = __builtin_amdgcn_s_getreg((7u << 11) | (8u << 6) | 4) & 0xff; // HW_ID[15:8]
  if (tid == 0) {
    st_sc1((uint64_t)&table[bid], xcd | (cuk << 3));
    drain_vm();
    atomicAdd(arrive, 1);
    int spins = 0;
    while (atomicAdd(arrive, 0) < NBLK && spins < (1 << 22)) {
      __builtin_amdgcn_s_sleep(8);
      ++spins;
    }
  }
  if (tid < 32) *(unsigned long long*)&seen[tid >> 2][tid & 3] = 0ull;
  __syncthreads();
  tbl[tid]       = ld_sc1((uint64_t)&table[tid]);
  tbl[tid + 256] = ld_sc1((uint64_t)&table[tid + 256]);
  __syncthreads();
  if (tid == 0) {
    int cnt[8]    = {0, 0, 0, 0, 0, 0, 0, 0};
    int wcount[8] = {0, 0, 0, 0, 0, 0, 0, 0};
    int my_rank = 0, my_w = -1;
    for (int j = 0; j < NBLK; ++j) {
      const int e  = tbl[j];
      const int xx = e & 7;
      const int ky = (e >> 3) & 0xff;
      const unsigned long long bit = 1ull << (ky & 63);
      const bool first = !(seen[xx][ky >> 6] & bit);
      if (first) seen[xx][ky >> 6] |= bit;
      int w = -1;
      if (first && wcount[xx] < 32) w = wcount[xx]++;
      if (j == bid) { my_rank = cnt[xx]; my_w = w; }
      cnt[xx]++;
    }
    int slot = my_w;
    if (wcount[xcd] != 32)                 // CU-key aliasing: safe fallback
      slot = (my_rank < 32) ? my_rank : -1;
    s_grp = (slot >= 0) ? xcd : -1;
    s_slot = slot;
    s_abort = 0;
  }
  __syncthreads();
  const int g    = s_grp;
  const int slot = s_slot;
  if (g < 0) return;                       // surplus block exits

  // ---- persistent weight fragments (B-frag: lane holds B[k=q*8+j][n=l15]) ----
  const int gcol = wave * H_DIM + slot * 16 + l15;   // gate row 0..2047
  s16x8 bhh_f[16];
#pragma unroll
  for (int kb = 0; kb < 16; ++kb) {
    const float* src = Whh + (size_t)gcol * H_DIM + kb * 32 + q * 8;
    s16x8 v;
#pragma unroll
    for (int i = 0; i < 8; ++i) v[i] = (short)f2bf(src[i]);
    bhh_f[kb] = v;
  }
  s16x8 bih_f[8];
#pragma unroll
  for (int kb = 0; kb < 8; ++kb) {
    const float* src = Wih + (size_t)gcol * I_DIM + kb * 32 + q * 8;
    s16x8 v;
#pragma unroll
    for (int i = 0; i < 8; ++i) v[i] = (short)f2bf(src[i]);
    bih_f[kb] = v;
  }
  const float bias_v = bih[gcol] + bhh[gcol];

  // ---- x staging geometry: thread covers row m0, cols kc0*16..+15 ----
  const int m0  = tid & 15;
  const int kc0 = tid >> 4;
  const int xkb   = kc0 >> 1;
  const int laneA = m0 + 32 * (kc0 & 1);
  const int laneB = laneA + 16;
  const float* const xrow = x + (size_t)(g * BC + m0) * S_LEN * I_DIM + kc0 * 16;

  // ---- preload: x[0] -> LDS parity 0; x[1] -> regs xN ----
  {
    float xt[16];
    *(float4*)&xt[0]  = ((const float4*)xrow)[0];
    *(float4*)&xt[4]  = ((const float4*)xrow)[1];
    *(float4*)&xt[8]  = ((const float4*)xrow)[2];
    *(float4*)&xt[12] = ((const float4*)xrow)[3];
    s16x8 v0, v1;
#pragma unroll
    for (int i = 0; i < 8; ++i) { v0[i] = (short)f2bf(xt[i]); v1[i] = (short)f2bf(xt[8 + i]); }
    *(s16x8*)&x_s[0][xkb][laneA * 8] = v0;
    *(s16x8*)&x_s[0][xkb][laneB * 8] = v1;
  }
  float xN[16];
  {
    const float* src = xrow + (size_t)1 * I_DIM;
    *(float4*)&xN[0]  = ((const float4*)src)[0];
    *(float4*)&xN[4]  = ((const float4*)src)[1];
    *(float4*)&xN[8]  = ((const float4*)src)[2];
    *(float4*)&xN[12] = ((const float4*)src)[3];
  }
  __syncthreads();

  // ---- mailbox addressing ----
  // my poll row: mbox[g][slot][p], p = 0..31 (one 64-B line per producer)
  int* const mybox = flags + ((size_t)(g * 32 + slot) * 32) * FSTRIDE;
  // my post targets: mbox[g][c][slot], c = lane 0..31
  const uint64_t post_base =
      (uint64_t)(flags + ((size_t)(g * 32) * 32 + slot) * FSTRIDE);
  const uint64_t post_addr = post_base + (uint64_t)(lane & 31) * (32 * FSTRIDE * 4);

  // producer store coordinates (fragment-order payload)
  const int erow  = wave * 4 + q;
  const int kcol  = slot * 16 + l15;
  const int sidx  = (kcol >> 5) * 512 + (erow + 16 * ((kcol >> 3) & 3)) * 8 + (kcol & 7);

  int p = 0;
  float c_reg = 0.0f;

  for (int t = 0; t < S_LEN; ++t) {
    // ---- 1) issue x[t+2] loads (consumed next step: HBM latency hidden) ----
    float xF[16];
    if (t + 2 < S_LEN) {
      const float* src = xrow + (size_t)(t + 2) * I_DIM;
      *(float4*)&xF[0]  = ((const float4*)src)[0];
      *(float4*)&xF[4]  = ((const float4*)src)[1];
      *(float4*)&xF[8]  = ((const float4*)src)[2];
      *(float4*)&xF[12] = ((const float4*)src)[3];
    }

    // ---- 2) x-part of gates from LDS ----
    f32x4 acc = {bias_v, bias_v, bias_v, bias_v};
#pragma unroll
    for (int kb = 0; kb < 8; ++kb) {
      s16x8 a = *(const s16x8*)&x_s[p][kb][lane * 8];
      acc = __builtin_amdgcn_mfma_f32_16x16x32_bf16(a, bih_f[kb], acc, 0, 0, 0);
    }

    // ---- 3) stash xN (= x[t+1], loaded a full step ago) into other parity ----
    if (t + 1 < S_LEN) {
      s16x8 v0, v1;
#pragma unroll
      for (int i = 0; i < 8; ++i) { v0[i] = (short)f2bf(xN[i]); v1[i] = (short)f2bf(xN[8 + i]); }
      *(s16x8*)&x_s[p ^ 1][xkb][laneA * 8] = v0;
      *(s16x8*)&x_s[p ^ 1][xkb][laneB * 8] = v1;
    }

    if (t > 0) {
      // ---- 4) 32-lane mailbox poll: each lane owns ONE line (queue<=2) ----
      if (tid < 32 && !s_abort) {
        const uint64_t a = (uint64_t)(mybox + (size_t)tid * FSTRIDE);
        int rounds = 0;
        for (;;) {
          int v = poll_local(a);
          if (__all(v >= t)) break;        // exec = lanes 0..31 only
          if (++rounds > (1 << 16)) { if (tid == 0) s_abort = 1; break; }
        }
      }
      __syncthreads();                             // B1: h_t published
      // ---- 4b) stage payload -> LDS once (plain loads; W=16 eviction) ----
      {
        const unsigned short* pb =
            hpay + (size_t)((t & wmask) * GROUPS + g) * PAYG + (size_t)tid * 8;
        s16x8 c0 = *(const s16x8*)(pb);
        s16x8 c1 = *(const s16x8*)(pb + 2048);
        s16x8 c2 = *(const s16x8*)(pb + 4096);
        s16x8 c3 = *(const s16x8*)(pb + 6144);
        *(s16x8*)&h_stage[tid * 8]        = c0;
        *(s16x8*)&h_stage[tid * 8 + 2048] = c1;
        *(s16x8*)&h_stage[tid * 8 + 4096] = c2;
        *(s16x8*)&h_stage[tid * 8 + 6144] = c3;
      }
      __syncthreads();                             // B2: h_stage ready
      f32x4 h0 = {0.f, 0.f, 0.f, 0.f}, h1 = {0.f, 0.f, 0.f, 0.f};
#pragma unroll
      for (int kb = 0; kb < 16; kb += 2) {
        const s16x8 a0 = *(const s16x8*)&h_stage[(kb    ) * 512 + lane * 8];
        const s16x8 a1 = *(const s16x8*)&h_stage[(kb + 1) * 512 + lane * 8];
        h0 = __builtin_amdgcn_mfma_f32_16x16x32_bf16(a0, bhh_f[kb],     h0, 0, 0, 0);
        h1 = __builtin_amdgcn_mfma_f32_16x16x32_bf16(a1, bhh_f[kb + 1], h1, 0, 0, 0);
      }
      acc += h0 + h1;
    }

    // ---- 5) publish gate section (C/D: col=l15, row=q*4+r) ----
#pragma unroll
    for (int r = 0; r < 4; ++r) gates[wave][q * 4 + r][l15] = acc[r];
    __syncthreads();                               // B3: gates ready

    // ---- 6) elementwise; lane owns (row=erow, col=kcol); store h_{t+1} ----
    {
      float yi = gates[0][erow][l15];
      float yf = gates[1][erow][l15];
      float yg = gates[2][erow][l15];
      float yo = gates[3][erow][l15];
      float ig = sigf(yi), fg = sigf(yf), gg = fmaxf(yg, 0.0f), og = sigf(yo);
      c_reg = fg * c_reg + ig * gg;
      float h = og * c_reg;
      hpay[(size_t)(((t + 1) & wmask) * GROUPS + g) * PAYG + sidx] = f2bf(h);
    }

    // ---- 7) drain stores, barrier, then 32-lane mailbox post (plain) ----
    drain_vm();
    __syncthreads();                               // B4: block fully drained
    if (tid < 32) st_flag(post_addr, t + 1);

    // ---- 8) advance pipeline ----
#pragma unroll
    for (int i = 0; i < 16; ++i) xN[i] = xF[i];
    p ^= 1;
  }

  // ---- final FC by slot-0 block; h_S in slot (S_LEN & wmask) == 0 ----
  if (slot == 0) {
    if (tid < 32 && !s_abort) {
      const uint64_t a = (uint64_t)(mybox + (size_t)tid * FSTRIDE);
      int rounds = 0;
      for (;;) {
        int v = poll_local(a);
        if (__all(v >= S_LEN)) break;
        if (++rounds > (1 << 16)) break;
      }
    }
    __syncthreads();
    unsigned short* hfc = &x_s[0][0][0];           // reuse as [16][512]
    {
      const unsigned short* pb = hpay + (size_t)g * PAYG + (size_t)tid * 32;
      s16x8 cc[4];
      cc[0] = ((const s16x8*)pb)[0];
      cc[1] = ((const s16x8*)pb)[1];
      cc[2] = ((const s16x8*)pb)[2];
      cc[3] = ((const s16x8*)pb)[3];
      const int kb = tid >> 4;
      const int L0 = (tid & 15) * 4;
#pragma unroll
      for (int i = 0; i < 4; ++i) {
        const int L = L0 + i;
        const int m = L & 15, qq = L >> 4;
        *(s16x8*)&hfc[m * 512 + kb * 32 + qq * 8] = cc[i];
      }
    }
    __syncthreads();

    if (tid < BC * 10) {
      const int row = tid / 10, o = tid - row * 10;
      const float* wr = fcw + (size_t)o * H_DIM;
      float sum = fcb[o];
      for (int k = 0; k < H_DIM; k += 8) {
#pragma unroll
        for (int j = 0; j < 8; ++j)
          sum += bf2f(hfc[row * 512 + k + j]) * wr[k + j];
      }
      out[(g * BC + row) * 10 + o] = sum;
    }
  }
}

extern "C" void kernel_launch(void* const* d_in, const int* in_sizes, int n_in,
                              void* d_out, int out_size, void* d_ws, size_t ws_size,
                              hipStream_t stream) {
  (void)in_sizes; (void)n_in; (void)out_size;
  const float* x   = (const float*)d_in[0];
  const float* Wih = (const float*)d_in[1];
  const float* Whh = (const float*)d_in[2];
  const float* bih = (const float*)d_in[3];
  const float* bhh = (const float*)d_in[4];
  const float* fcw = (const float*)d_in[5];
  const float* fcb = (const float*)d_in[6];

  int* arrive = (int*)d_ws;                          // @0
  int* table  = (int*)((char*)d_ws + 4096);          // @4K, 512 ints
  int* flags  = (int*)((char*)d_ws + 8192);          // @8K, mailbox matrix (512 KB)
  unsigned short* hpay = (unsigned short*)((char*)d_ws + HPAY_OFF);

  // rotation depth W: power of two, 2..16 (16 => ~512 KB vL1 turnover per
  // address reuse -- the PROVEN plain-load freshness mechanism)
  size_t avail = ws_size > HPAY_OFF ? ws_size - HPAY_OFF : 0;
  int W = 2;
  while (W < 16 && (size_t)(W * 2) * (PAYSLOT * 2) <= avail) W <<= 1;

  // zero arrive + table + mailbox region (mailboxes MUST start at 0;
  // re-zeroed every launch -> graph-replay safe)
  hipMemsetAsync(d_ws, 0, HPAY_OFF, stream);

  hipLaunchKernelGGL(lstm_persistent, dim3(NBLK), dim3(256), 0, stream,
                     x, Wih, Whh, bih, bhh, fcw, fcb, (float*)d_out,
                     arrive, table, flags, hpay, W - 1);
}

// Round 6
// 2316.890 us; speedup vs baseline: 1.3066x; 1.3066x over previous
//
#include <hip/hip_runtime.h>
#include <stdint.h>

// ---------------------------------------------------------------------------
// Persistent-kernel LSTM (relu g-gate, h = o*c, no tanh).
// B=128, S=1024, I=256, H=512, O=10.
//
// R13 = R11 (best: 2271 us; 4 sub-counter sync, LDS payload staging, W=16
// capacity-eviction freshness) + three latency micro-cuts:
//  * v_cvt_pk_bf16_f32 for x-stash (48 VALU ops -> 8 instr) and h pack.
//  * xN->xF register copy eliminated: stash x[t+1] from xN FIRST, then
//    refill the same regs with x[t+2] (issue order makes this safe).
//  * s_sleep(2) backoff in poll loops: 32 spinning add0 RMWs saturate the
//    counter line's TCC queue (~30-40cy service); the producer's add-1 post
//    queues behind ~30 of them (~1000cy discovery). Lower poll rate ->
//    shorter queue for the post to penetrate.
// Sync/freshness semantics are UNCHANGED from R11 (R12 lesson: posts must
// touch O(1) lines per block per step -- fan-out posts cost 64B EA writes
// per line per step and their visibility latency).
// ---------------------------------------------------------------------------

#define GROUPS 8
#define BC     16
#define S_LEN  1024
#define I_DIM  256
#define H_DIM  512
#define NBLK   512
#define FSTRIDE 16                    // flag stride unit (64 B)
#define SUBSTRIDE 64                  // sub-counter stride in ints (256 B)
#define PAYG   (BC * H_DIM)           // 8192 shorts per group per slot
#define PAYSLOT (GROUPS * PAYG)       // shorts per rotation slot

typedef float f32x4 __attribute__((ext_vector_type(4)));
typedef short s16x8 __attribute__((ext_vector_type(8)));
typedef unsigned u32x4 __attribute__((ext_vector_type(4)));

__device__ __forceinline__ unsigned short f2bf(float f) {
  unsigned u = __float_as_uint(f);
  u += 0x7fffu + ((u >> 16) & 1u);   // RNE
  return (unsigned short)(u >> 16);
}
__device__ __forceinline__ float bf2f(unsigned short h) {
  return __uint_as_float(((unsigned)h) << 16);
}
__device__ __forceinline__ float sigf(float x) { return 1.0f / (1.0f + __expf(-x)); }

// HW packed f32->bf16 (RNE), 2 values per instruction.
__device__ __forceinline__ unsigned cvt_pk_bf16(float lo, float hi) {
  unsigned r;
  asm("v_cvt_pk_bf16_f32 %0, %1, %2" : "=v"(r) : "v"(lo), "v"(hi));
  return r;
}

// TCC-executed read (atomic add 0, returns old): PROVEN fresh on gfx950.
__device__ __forceinline__ int poll_local(uint64_t a) {
  int v;
  asm volatile("global_atomic_add %0, %1, %2, off sc0\n\ts_waitcnt vmcnt(0)"
               : "=v"(v) : "v"(a), "v"(0) : "memory");
  return v;
}
__device__ __forceinline__ int ld_sc1(uint64_t a) {
  int v;
  asm volatile("global_load_dword %0, %1, off sc1\n\ts_waitcnt vmcnt(0)"
               : "=v"(v) : "v"(a) : "memory");
  return v;
}
__device__ __forceinline__ void st_sc1(uint64_t a, int v) {
  asm volatile("global_store_dword %0, %1, off sc1" :: "v"(a), "v"(v) : "memory");
}
__device__ __forceinline__ void drain_vm() {
  asm volatile("s_waitcnt vmcnt(0)" ::: "memory");
}

__global__ __launch_bounds__(256, 2)
void lstm_persistent(const float* __restrict__ x,
                     const float* __restrict__ Wih,
                     const float* __restrict__ Whh,
                     const float* __restrict__ bih,
                     const float* __restrict__ bhh,
                     const float* __restrict__ fcw,
                     const float* __restrict__ fcb,
                     float* __restrict__ out,
                     int* __restrict__ arrive,           // [1], zeroed
                     int* __restrict__ table,            // [NBLK]
                     int* __restrict__ flags,            // counters, zeroed
                     unsigned short* __restrict__ hpay,  // [W][GROUPS][PAYG]
                     int wmask)
{
  __shared__ __align__(16) unsigned short x_s[2][8][512];  // fragment-order x
  __shared__ __align__(16) unsigned short h_stage[8192];   // one group-slot of h
  __shared__ __align__(16) float gates[4][BC][18];
  __shared__ int tbl[NBLK];
  __shared__ unsigned long long seen[GROUPS][4];
  __shared__ int s_grp, s_slot, s_abort;

  const int tid  = threadIdx.x;
  const int wave = tid >> 6;        // gate section 0..3 (i,f,g,o)
  const int lane = tid & 63;
  const int q    = lane >> 4;
  const int l15  = lane & 15;
  const int bid  = blockIdx.x;

  // ---- rendezvous: publish (xcd, cu-key), wait for all, elect workers ----
  const int xcd = __builtin_amdgcn_s_getreg((31u << 11) | 20) & 7;     // XCC_ID
  const int cuk = __builtin_amdgcn_s_getreg((7u << 11) | (8u << 6) | 4) & 0xff; // HW_ID[15:8]
  if (tid == 0) {
    st_sc1((uint64_t)&table[bid], xcd | (cuk << 3));
    drain_vm();
    atomicAdd(arrive, 1);
    int spins = 0;
    while (atomicAdd(arrive, 0) < NBLK && spins < (1 << 22)) {
      __builtin_amdgcn_s_sleep(8);
      ++spins;
    }
  }
  if (tid < 32) *(unsigned long long*)&seen[tid >> 2][tid & 3] = 0ull;
  __syncthreads();
  tbl[tid]       = ld_sc1((uint64_t)&table[tid]);
  tbl[tid + 256] = ld_sc1((uint64_t)&table[tid + 256]);
  __syncthreads();
  if (tid == 0) {
    int cnt[8]    = {0, 0, 0, 0, 0, 0, 0, 0};
    int wcount[8] = {0, 0, 0, 0, 0, 0, 0, 0};
    int my_rank = 0, my_w = -1;
    for (int j = 0; j < NBLK; ++j) {
      const int e  = tbl[j];
      const int xx = e & 7;
      const int ky = (e >> 3) & 0xff;
      const unsigned long long bit = 1ull << (ky & 63);
      const bool first = !(seen[xx][ky >> 6] & bit);
      if (first) seen[xx][ky >> 6] |= bit;
      int w = -1;
      if (first && wcount[xx] < 32) w = wcount[xx]++;
      if (j == bid) { my_rank = cnt[xx]; my_w = w; }
      cnt[xx]++;
    }
    int slot = my_w;
    if (wcount[xcd] != 32)                 // CU-key aliasing: safe fallback
      slot = (my_rank < 32) ? my_rank : -1;
    s_grp = (slot >= 0) ? xcd : -1;
    s_slot = slot;
    s_abort = 0;
  }
  __syncthreads();
  const int g    = s_grp;
  const int slot = s_slot;
  if (g < 0) return;                       // surplus block exits

  // ---- persistent weight fragments (B-frag: lane holds B[k=q*8+j][n=l15]) ----
  const int gcol = wave * H_DIM + slot * 16 + l15;   // gate row 0..2047
  s16x8 bhh_f[16];
#pragma unroll
  for (int kb = 0; kb < 16; ++kb) {
    const float* src = Whh + (size_t)gcol * H_DIM + kb * 32 + q * 8;
    s16x8 v;
#pragma unroll
    for (int i = 0; i < 8; ++i) v[i] = (short)f2bf(src[i]);
    bhh_f[kb] = v;
  }
  s16x8 bih_f[8];
#pragma unroll
  for (int kb = 0; kb < 8; ++kb) {
    const float* src = Wih + (size_t)gcol * I_DIM + kb * 32 + q * 8;
    s16x8 v;
#pragma unroll
    for (int i = 0; i < 8; ++i) v[i] = (short)f2bf(src[i]);
    bih_f[kb] = v;
  }
  const float bias_v = bih[gcol] + bhh[gcol];

  // ---- x staging geometry: thread covers row m0, cols kc0*16..+15 ----
  const int m0  = tid & 15;
  const int kc0 = tid >> 4;
  const int xkb   = kc0 >> 1;
  const int laneA = m0 + 32 * (kc0 & 1);
  const int laneB = laneA + 16;
  const float* const xrow = x + (size_t)(g * BC + m0) * S_LEN * I_DIM + kc0 * 16;

  // ---- preload: x[0] -> LDS parity 0; x[1] -> regs xN ----
  {
    float xt[16];
    *(float4*)&xt[0]  = ((const float4*)xrow)[0];
    *(float4*)&xt[4]  = ((const float4*)xrow)[1];
    *(float4*)&xt[8]  = ((const float4*)xrow)[2];
    *(float4*)&xt[12] = ((const float4*)xrow)[3];
    u32x4 v0, v1;
#pragma unroll
    for (int i = 0; i < 4; ++i) {
      v0[i] = cvt_pk_bf16(xt[2 * i],     xt[2 * i + 1]);
      v1[i] = cvt_pk_bf16(xt[8 + 2 * i], xt[8 + 2 * i + 1]);
    }
    *(u32x4*)&x_s[0][xkb][laneA * 8] = v0;
    *(u32x4*)&x_s[0][xkb][laneB * 8] = v1;
  }
  float xN[16];
  {
    const float* src = xrow + (size_t)1 * I_DIM;
    *(float4*)&xN[0]  = ((const float4*)src)[0];
    *(float4*)&xN[4]  = ((const float4*)src)[1];
    *(float4*)&xN[8]  = ((const float4*)src)[2];
    *(float4*)&xN[12] = ((const float4*)src)[3];
  }
  __syncthreads();

  // per-group sub-counters: 4 lines, 256 B apart, zeroed at launch
  int* const gcnt = flags + (size_t)g * 32 * FSTRIDE;

  // producer store coordinates (fragment-order payload)
  const int erow  = wave * 4 + q;
  const int kcol  = slot * 16 + l15;
  const int sidx  = (kcol >> 5) * 512 + (erow + 16 * ((kcol >> 3) & 3)) * 8 + (kcol & 7);

  int p = 0;
  float c_reg = 0.0f;

  for (int t = 0; t < S_LEN; ++t) {
    // ---- 1) stash xN (= x[t+1]) into other parity (cvt_pk, 8 instr) ----
    if (t + 1 < S_LEN) {
      u32x4 v0, v1;
#pragma unroll
      for (int i = 0; i < 4; ++i) {
        v0[i] = cvt_pk_bf16(xN[2 * i],     xN[2 * i + 1]);
        v1[i] = cvt_pk_bf16(xN[8 + 2 * i], xN[8 + 2 * i + 1]);
      }
      *(u32x4*)&x_s[p ^ 1][xkb][laneA * 8] = v0;
      *(u32x4*)&x_s[p ^ 1][xkb][laneB * 8] = v1;
    }

    // ---- 2) refill xN <- x[t+2] (same regs; ds_write above issued first) ----
    if (t + 2 < S_LEN) {
      const float* src = xrow + (size_t)(t + 2) * I_DIM;
      *(float4*)&xN[0]  = ((const float4*)src)[0];
      *(float4*)&xN[4]  = ((const float4*)src)[1];
      *(float4*)&xN[8]  = ((const float4*)src)[2];
      *(float4*)&xN[12] = ((const float4*)src)[3];
    }

    // ---- 3) x-part of gates from LDS ----
    f32x4 acc = {bias_v, bias_v, bias_v, bias_v};
#pragma unroll
    for (int kb = 0; kb < 8; ++kb) {
      s16x8 a = *(const s16x8*)&x_s[p][kb][lane * 8];
      acc = __builtin_amdgcn_mfma_f32_16x16x32_bf16(a, bih_f[kb], acc, 0, 0, 0);
    }

    if (t > 0) {
      // ---- 4) 4-lane poll of 4 sub-counter lines, with backoff ----
      if (tid < 4 && !s_abort) {
        const uint64_t a = (uint64_t)(gcnt + (size_t)tid * SUBSTRIDE);
        const int need = 8 * t;
        int rounds = 0;
        for (;;) {
          int v = poll_local(a);
          if (__all(v >= need)) break;     // exec = lanes 0..3 only
          if (++rounds > (1 << 16)) { if (tid == 0) s_abort = 1; break; }
          __builtin_amdgcn_s_sleep(2);     // cut atomic-queue pressure
        }
      }
      __syncthreads();                             // B1: h_t published
      // ---- 4b) stage payload -> LDS once (plain loads; W=16 eviction) ----
      {
        const unsigned short* pb =
            hpay + (size_t)((t & wmask) * GROUPS + g) * PAYG + (size_t)tid * 8;
        s16x8 c0 = *(const s16x8*)(pb);
        s16x8 c1 = *(const s16x8*)(pb + 2048);
        s16x8 c2 = *(const s16x8*)(pb + 4096);
        s16x8 c3 = *(const s16x8*)(pb + 6144);
        *(s16x8*)&h_stage[tid * 8]        = c0;
        *(s16x8*)&h_stage[tid * 8 + 2048] = c1;
        *(s16x8*)&h_stage[tid * 8 + 4096] = c2;
        *(s16x8*)&h_stage[tid * 8 + 6144] = c3;
      }
      __syncthreads();                             // B2: h_stage ready
      f32x4 h0 = {0.f, 0.f, 0.f, 0.f}, h1 = {0.f, 0.f, 0.f, 0.f};
#pragma unroll
      for (int kb = 0; kb < 16; kb += 2) {
        const s16x8 a0 = *(const s16x8*)&h_stage[(kb    ) * 512 + lane * 8];
        const s16x8 a1 = *(const s16x8*)&h_stage[(kb + 1) * 512 + lane * 8];
        h0 = __builtin_amdgcn_mfma_f32_16x16x32_bf16(a0, bhh_f[kb],     h0, 0, 0, 0);
        h1 = __builtin_amdgcn_mfma_f32_16x16x32_bf16(a1, bhh_f[kb + 1], h1, 0, 0, 0);
      }
      acc += h0 + h1;
    }

    // ---- 5) publish gate section (C/D: col=l15, row=q*4+r) ----
#pragma unroll
    for (int r = 0; r < 4; ++r) gates[wave][q * 4 + r][l15] = acc[r];
    __syncthreads();                               // B3: gates ready

    // ---- 6) elementwise; lane owns (row=erow, col=kcol); store h_{t+1} ----
    {
      float yi = gates[0][erow][l15];
      float yf = gates[1][erow][l15];
      float yg = gates[2][erow][l15];
      float yo = gates[3][erow][l15];
      float ig = sigf(yi), fg = sigf(yf), gg = fmaxf(yg, 0.0f), og = sigf(yo);
      c_reg = fg * c_reg + ig * gg;
      float h = og * c_reg;
      hpay[(size_t)(((t + 1) & wmask) * GROUPS + g) * PAYG + sidx] =
          (unsigned short)cvt_pk_bf16(h, h);
    }

    // ---- 7) drain stores (all threads), barrier, then ONE counter post ----
    drain_vm();
    __syncthreads();                               // B4: block fully drained
    if (tid == 0) atomicAdd(gcnt + (size_t)(slot & 3) * SUBSTRIDE, 1);

    // ---- 8) advance parity ----
    p ^= 1;
  }

  // ---- final FC by slot-0 block; h_S in slot (S_LEN & wmask) == 0 ----
  if (slot == 0) {
    if (tid < 4 && !s_abort) {
      const uint64_t a = (uint64_t)(gcnt + (size_t)tid * SUBSTRIDE);
      const int need = 8 * S_LEN;
      int rounds = 0;
      for (;;) {
        int v = poll_local(a);
        if (__all(v >= need)) break;
        if (++rounds > (1 << 16)) break;
        __builtin_amdgcn_s_sleep(2);
      }
    }
    __syncthreads();
    unsigned short* hfc = &x_s[0][0][0];           // reuse as [16][512]
    {
      const unsigned short* pb = hpay + (size_t)g * PAYG + (size_t)tid * 32;
      s16x8 cc[4];
      cc[0] = ((const s16x8*)pb)[0];
      cc[1] = ((const s16x8*)pb)[1];
      cc[2] = ((const s16x8*)pb)[2];
      cc[3] = ((const s16x8*)pb)[3];
      const int kb = tid >> 4;
      const int L0 = (tid & 15) * 4;
#pragma unroll
      for (int i = 0; i < 4; ++i) {
        const int L = L0 + i;
        const int m = L & 15, qq = L >> 4;
        *(s16x8*)&hfc[m * 512 + kb * 32 + qq * 8] = cc[i];
      }
    }
    __syncthreads();

    if (tid < BC * 10) {
      const int row = tid / 10, o = tid - row * 10;
      const float* wr = fcw + (size_t)o * H_DIM;
      float sum = fcb[o];
      for (int k = 0; k < H_DIM; k += 8) {
#pragma unroll
        for (int j = 0; j < 8; ++j)
          sum += bf2f(hfc[row * 512 + k + j]) * wr[k + j];
      }
      out[(g * BC + row) * 10 + o] = sum;
    }
  }
}

extern "C" void kernel_launch(void* const* d_in, const int* in_sizes, int n_in,
                              void* d_out, int out_size, void* d_ws, size_t ws_size,
                              hipStream_t stream) {
  (void)in_sizes; (void)n_in; (void)out_size;
  const float* x   = (const float*)d_in[0];
  const float* Wih = (const float*)d_in[1];
  const float* Whh = (const float*)d_in[2];
  const float* bih = (const float*)d_in[3];
  const float* bhh = (const float*)d_in[4];
  const float* fcw = (const float*)d_in[5];
  const float* fcb = (const float*)d_in[6];

  int* arrive = (int*)d_ws;                          // @0
  int* table  = (int*)((char*)d_ws + 4096);          // @4K, 512 ints
  int* flags  = (int*)((char*)d_ws + 8192);          // @8K, per-group sub-counters
  unsigned short* hpay = (unsigned short*)((char*)d_ws + 32768);

  // rotation depth W: power of two, 2..16 (16 => ~512 KB vL1 turnover per
  // address reuse -- the PROVEN plain-load freshness mechanism)
  size_t avail = ws_size > 32768 ? ws_size - 32768 : 0;
  int W = 2;
  while (W < 16 && (size_t)(W * 2) * (PAYSLOT * 2) <= avail) W <<= 1;

  // zero arrive + table + counter region (counters MUST start at 0;
  // re-zeroed every launch -> graph-replay safe)
  hipMemsetAsync(d_ws, 0, 32768, stream);

  hipLaunchKernelGGL(lstm_persistent, dim3(NBLK), dim3(256), 0, stream,
                     x, Wih, Whh, bih, bhh, fcw, fcb, (float*)d_out,
                     arrive, table, flags, hpay, W - 1);
}

// Round 7
// 2296.262 us; speedup vs baseline: 1.3183x; 1.0090x over previous
//
#include <hip/hip_runtime.h>
#include <stdint.h>

// ---------------------------------------------------------------------------
// Persistent-kernel LSTM (relu g-gate, h = o*c, no tanh).
// B=128, S=1024, I=256, H=512, O=10.
//
// R14 = R13 structure (LDS payload staging, W=16 capacity-eviction
// freshness, cvt_pk packing) with the sync path moved off device-scope
// atomics onto the XCD-local L2:
//  * Per-slot flag lines (flags[g][slot], 64 B apart). Producer posts ONE
//    plain store (t+1) to its own line after drain+B4  [R7-proven path;
//    respects the R12 law: O(1) posted lines per block per step].
//  * Consumer polls 32 lines with 32 lanes using global_load_dword `nt`
//    (non-temporal: no L1 allocation -> every round re-reads the XCD L2,
//    where the producer's plain store landed). ~250-300 cy per round vs
//    ~600-900 cy for the device-coherence-point atomic RMW.
//  * SAFETY: every 4th round falls back to the PROVEN TCC atomic read on
//    the same lines. If `nt` freshness fails on gfx950, correctness is
//    preserved (discovery just costs more); if it works, both sync hops
//    (post + discover) become L2-local.
//  * No steady-state atomics => no RMW dirtying of flag lines at the
//    coherence point (R7's 538 MB / R11's 44 MB WRITE_SIZE signature).
// ---------------------------------------------------------------------------

#define GROUPS 8
#define BC     16
#define S_LEN  1024
#define I_DIM  256
#define H_DIM  512
#define NBLK   512
#define FSTRIDE 16                    // flag stride in ints (64 B)
#define PAYG   (BC * H_DIM)           // 8192 shorts per group per slot
#define PAYSLOT (GROUPS * PAYG)       // shorts per rotation slot

typedef float f32x4 __attribute__((ext_vector_type(4)));
typedef short s16x8 __attribute__((ext_vector_type(8)));
typedef unsigned u32x4 __attribute__((ext_vector_type(4)));

__device__ __forceinline__ unsigned short f2bf(float f) {
  unsigned u = __float_as_uint(f);
  u += 0x7fffu + ((u >> 16) & 1u);   // RNE
  return (unsigned short)(u >> 16);
}
__device__ __forceinline__ float bf2f(unsigned short h) {
  return __uint_as_float(((unsigned)h) << 16);
}
__device__ __forceinline__ float sigf(float x) { return 1.0f / (1.0f + __expf(-x)); }

// HW packed f32->bf16 (RNE), 2 values per instruction.
__device__ __forceinline__ unsigned cvt_pk_bf16(float lo, float hi) {
  unsigned r;
  asm("v_cvt_pk_bf16_f32 %0, %1, %2" : "=v"(r) : "v"(lo), "v"(hi));
  return r;
}

// TCC-executed read (atomic add 0, returns old): PROVEN fresh on gfx950.
__device__ __forceinline__ int poll_local(uint64_t a) {
  int v;
  asm volatile("global_atomic_add %0, %1, %2, off sc0\n\ts_waitcnt vmcnt(0)"
               : "=v"(v) : "v"(a), "v"(0) : "memory");
  return v;
}
// Non-temporal load: no L1 allocation -> re-reads XCD L2 each round.
// UNVERIFIED freshness; always paired with periodic poll_local fallback.
__device__ __forceinline__ int poll_nt(uint64_t a) {
  int v;
  asm volatile("global_load_dword %0, %1, off nt\n\ts_waitcnt vmcnt(0)"
               : "=v"(v) : "v"(a) : "memory");
  return v;
}
__device__ __forceinline__ int ld_sc1(uint64_t a) {
  int v;
  asm volatile("global_load_dword %0, %1, off sc1\n\ts_waitcnt vmcnt(0)"
               : "=v"(v) : "v"(a) : "memory");
  return v;
}
__device__ __forceinline__ void st_sc1(uint64_t a, int v) {
  asm volatile("global_store_dword %0, %1, off sc1" :: "v"(a), "v"(v) : "memory");
}
__device__ __forceinline__ void st_flag(uint64_t a, int v) {
  asm volatile("global_store_dword %0, %1, off" :: "v"(a), "v"(v) : "memory");
}
__device__ __forceinline__ void drain_vm() {
  asm volatile("s_waitcnt vmcnt(0)" ::: "memory");
}

__global__ __launch_bounds__(256, 2)
void lstm_persistent(const float* __restrict__ x,
                     const float* __restrict__ Wih,
                     const float* __restrict__ Whh,
                     const float* __restrict__ bih,
                     const float* __restrict__ bhh,
                     const float* __restrict__ fcw,
                     const float* __restrict__ fcb,
                     float* __restrict__ out,
                     int* __restrict__ arrive,           // [1], zeroed
                     int* __restrict__ table,            // [NBLK]
                     int* __restrict__ flags,            // [GROUPS][32][FSTRIDE]
                     unsigned short* __restrict__ hpay,  // [W][GROUPS][PAYG]
                     int wmask)
{
  __shared__ __align__(16) unsigned short x_s[2][8][512];  // fragment-order x
  __shared__ __align__(16) unsigned short h_stage[8192];   // one group-slot of h
  __shared__ __align__(16) float gates[4][BC][18];
  __shared__ int tbl[NBLK];
  __shared__ unsigned long long seen[GROUPS][4];
  __shared__ int s_grp, s_slot, s_abort;

  const int tid  = threadIdx.x;
  const int wave = tid >> 6;        // gate section 0..3 (i,f,g,o)
  const int lane = tid & 63;
  const int q    = lane >> 4;
  const int l15  = lane & 15;
  const int bid  = blockIdx.x;

  // ---- rendezvous: publish (xcd, cu-key), wait for all, elect workers ----
  const int xcd = __builtin_amdgcn_s_getreg((31u << 11) | 20) & 7;     // XCC_ID
  const int cuk = __builtin_amdgcn_s_getreg((7u << 11) | (8u << 6) | 4) & 0xff; // HW_ID[15:8]
  if (tid == 0) {
    st_sc1((uint64_t)&table[bid], xcd | (cuk << 3));
    drain_vm();
    atomicAdd(arrive, 1);
    int spins = 0;
    while (atomicAdd(arrive, 0) < NBLK && spins < (1 << 22)) {
      __builtin_amdgcn_s_sleep(8);
      ++spins;
    }
  }
  if (tid < 32) *(unsigned long long*)&seen[tid >> 2][tid & 3] = 0ull;
  __syncthreads();
  tbl[tid]       = ld_sc1((uint64_t)&table[tid]);
  tbl[tid + 256] = ld_sc1((uint64_t)&table[tid + 256]);
  __syncthreads();
  if (tid == 0) {
    int cnt[8]    = {0, 0, 0, 0, 0, 0, 0, 0};
    int wcount[8] = {0, 0, 0, 0, 0, 0, 0, 0};
    int my_rank = 0, my_w = -1;
    for (int j = 0; j < NBLK; ++j) {
      const int e  = tbl[j];
      const int xx = e & 7;
      const int ky = (e >> 3) & 0xff;
      const unsigned long long bit = 1ull << (ky & 63);
      const bool first = !(seen[xx][ky >> 6] & bit);
      if (first) seen[xx][ky >> 6] |= bit;
      int w = -1;
      if (first && wcount[xx] < 32) w = wcount[xx]++;
      if (j == bid) { my_rank = cnt[xx]; my_w = w; }
      cnt[xx]++;
    }
    int slot = my_w;
    if (wcount[xcd] != 32)                 // CU-key aliasing: safe fallback
      slot = (my_rank < 32) ? my_rank : -1;
    s_grp = (slot >= 0) ? xcd : -1;
    s_slot = slot;
    s_abort = 0;
  }
  __syncthreads();
  const int g    = s_grp;
  const int slot = s_slot;
  if (g < 0) return;                       // surplus block exits

  // ---- persistent weight fragments (B-frag: lane holds B[k=q*8+j][n=l15]) ----
  const int gcol = wave * H_DIM + slot * 16 + l15;   // gate row 0..2047
  s16x8 bhh_f[16];
#pragma unroll
  for (int kb = 0; kb < 16; ++kb) {
    const float* src = Whh + (size_t)gcol * H_DIM + kb * 32 + q * 8;
    s16x8 v;
#pragma unroll
    for (int i = 0; i < 8; ++i) v[i] = (short)f2bf(src[i]);
    bhh_f[kb] = v;
  }
  s16x8 bih_f[8];
#pragma unroll
  for (int kb = 0; kb < 8; ++kb) {
    const float* src = Wih + (size_t)gcol * I_DIM + kb * 32 + q * 8;
    s16x8 v;
#pragma unroll
    for (int i = 0; i < 8; ++i) v[i] = (short)f2bf(src[i]);
    bih_f[kb] = v;
  }
  const float bias_v = bih[gcol] + bhh[gcol];

  // ---- x staging geometry: thread covers row m0, cols kc0*16..+15 ----
  const int m0  = tid & 15;
  const int kc0 = tid >> 4;
  const int xkb   = kc0 >> 1;
  const int laneA = m0 + 32 * (kc0 & 1);
  const int laneB = laneA + 16;
  const float* const xrow = x + (size_t)(g * BC + m0) * S_LEN * I_DIM + kc0 * 16;

  // ---- preload: x[0] -> LDS parity 0; x[1] -> regs xN ----
  {
    float xt[16];
    *(float4*)&xt[0]  = ((const float4*)xrow)[0];
    *(float4*)&xt[4]  = ((const float4*)xrow)[1];
    *(float4*)&xt[8]  = ((const float4*)xrow)[2];
    *(float4*)&xt[12] = ((const float4*)xrow)[3];
    u32x4 v0, v1;
#pragma unroll
    for (int i = 0; i < 4; ++i) {
      v0[i] = cvt_pk_bf16(xt[2 * i],     xt[2 * i + 1]);
      v1[i] = cvt_pk_bf16(xt[8 + 2 * i], xt[8 + 2 * i + 1]);
    }
    *(u32x4*)&x_s[0][xkb][laneA * 8] = v0;
    *(u32x4*)&x_s[0][xkb][laneB * 8] = v1;
  }
  float xN[16];
  {
    const float* src = xrow + (size_t)1 * I_DIM;
    *(float4*)&xN[0]  = ((const float4*)src)[0];
    *(float4*)&xN[4]  = ((const float4*)src)[1];
    *(float4*)&xN[8]  = ((const float4*)src)[2];
    *(float4*)&xN[12] = ((const float4*)src)[3];
  }
  __syncthreads();

  // ---- flag addressing: one 64-B line per producer slot ----
  int* const     fgrp  = flags + (size_t)g * 32 * FSTRIDE;
  const uint64_t fpoll = (uint64_t)(fgrp + (size_t)(tid & 31) * FSTRIDE);
  const uint64_t fmine = (uint64_t)(fgrp + (size_t)slot * FSTRIDE);

  // producer store coordinates (fragment-order payload)
  const int erow  = wave * 4 + q;
  const int kcol  = slot * 16 + l15;
  const int sidx  = (kcol >> 5) * 512 + (erow + 16 * ((kcol >> 3) & 3)) * 8 + (kcol & 7);

  int p = 0;
  float c_reg = 0.0f;

  for (int t = 0; t < S_LEN; ++t) {
    // ---- 1) stash xN (= x[t+1]) into other parity (cvt_pk, 8 instr) ----
    if (t + 1 < S_LEN) {
      u32x4 v0, v1;
#pragma unroll
      for (int i = 0; i < 4; ++i) {
        v0[i] = cvt_pk_bf16(xN[2 * i],     xN[2 * i + 1]);
        v1[i] = cvt_pk_bf16(xN[8 + 2 * i], xN[8 + 2 * i + 1]);
      }
      *(u32x4*)&x_s[p ^ 1][xkb][laneA * 8] = v0;
      *(u32x4*)&x_s[p ^ 1][xkb][laneB * 8] = v1;
    }

    // ---- 2) refill xN <- x[t+2] (same regs; ds_write above issued first) ----
    if (t + 2 < S_LEN) {
      const float* src = xrow + (size_t)(t + 2) * I_DIM;
      *(float4*)&xN[0]  = ((const float4*)src)[0];
      *(float4*)&xN[4]  = ((const float4*)src)[1];
      *(float4*)&xN[8]  = ((const float4*)src)[2];
      *(float4*)&xN[12] = ((const float4*)src)[3];
    }

    // ---- 3) x-part of gates from LDS ----
    f32x4 acc = {bias_v, bias_v, bias_v, bias_v};
#pragma unroll
    for (int kb = 0; kb < 8; ++kb) {
      s16x8 a = *(const s16x8*)&x_s[p][kb][lane * 8];
      acc = __builtin_amdgcn_mfma_f32_16x16x32_bf16(a, bih_f[kb], acc, 0, 0, 0);
    }

    if (t > 0) {
      // ---- 4) 32-lane flag poll: nt loads (L2-local), atomic every 4th ----
      if (tid < 32 && !s_abort) {
        int rounds = 0;
        for (;;) {
          int v = ((rounds & 3) == 3) ? poll_local(fpoll) : poll_nt(fpoll);
          if (__all(v >= t)) break;        // exec = lanes 0..31 only
          if (++rounds > (1 << 16)) { if (tid == 0) s_abort = 1; break; }
        }
      }
      __syncthreads();                             // B1: h_t published
      // ---- 4b) stage payload -> LDS once (plain loads; W=16 eviction) ----
      {
        const unsigned short* pb =
            hpay + (size_t)((t & wmask) * GROUPS + g) * PAYG + (size_t)tid * 8;
        s16x8 c0 = *(const s16x8*)(pb);
        s16x8 c1 = *(const s16x8*)(pb + 2048);
        s16x8 c2 = *(const s16x8*)(pb + 4096);
        s16x8 c3 = *(const s16x8*)(pb + 6144);
        *(s16x8*)&h_stage[tid * 8]        = c0;
        *(s16x8*)&h_stage[tid * 8 + 2048] = c1;
        *(s16x8*)&h_stage[tid * 8 + 4096] = c2;
        *(s16x8*)&h_stage[tid * 8 + 6144] = c3;
      }
      __syncthreads();                             // B2: h_stage ready
      f32x4 h0 = {0.f, 0.f, 0.f, 0.f}, h1 = {0.f, 0.f, 0.f, 0.f};
#pragma unroll
      for (int kb = 0; kb < 16; kb += 2) {
        const s16x8 a0 = *(const s16x8*)&h_stage[(kb    ) * 512 + lane * 8];
        const s16x8 a1 = *(const s16x8*)&h_stage[(kb + 1) * 512 + lane * 8];
        h0 = __builtin_amdgcn_mfma_f32_16x16x32_bf16(a0, bhh_f[kb],     h0, 0, 0, 0);
        h1 = __builtin_amdgcn_mfma_f32_16x16x32_bf16(a1, bhh_f[kb + 1], h1, 0, 0, 0);
      }
      acc += h0 + h1;
    }

    // ---- 5) publish gate section (C/D: col=l15, row=q*4+r) ----
#pragma unroll
    for (int r = 0; r < 4; ++r) gates[wave][q * 4 + r][l15] = acc[r];
    __syncthreads();                               // B3: gates ready

    // ---- 6) elementwise; lane owns (row=erow, col=kcol); store h_{t+1} ----
    {
      float yi = gates[0][erow][l15];
      float yf = gates[1][erow][l15];
      float yg = gates[2][erow][l15];
      float yo = gates[3][erow][l15];
      float ig = sigf(yi), fg = sigf(yf), gg = fmaxf(yg, 0.0f), og = sigf(yo);
      c_reg = fg * c_reg + ig * gg;
      float h = og * c_reg;
      hpay[(size_t)(((t + 1) & wmask) * GROUPS + g) * PAYG + sidx] =
          (unsigned short)cvt_pk_bf16(h, h);
    }

    // ---- 7) drain stores, barrier, then ONE plain flag store ----
    drain_vm();
    __syncthreads();                               // B4: block fully drained
    if (tid == 0) st_flag(fmine, t + 1);

    // ---- 8) advance parity ----
    p ^= 1;
  }

  // ---- final FC by slot-0 block; h_S in slot (S_LEN & wmask) == 0 ----
  if (slot == 0) {
    if (tid < 32 && !s_abort) {
      int rounds = 0;
      for (;;) {
        int v = ((rounds & 3) == 3) ? poll_local(fpoll) : poll_nt(fpoll);
        if (__all(v >= S_LEN)) break;
        if (++rounds > (1 << 16)) break;
      }
    }
    __syncthreads();
    unsigned short* hfc = &x_s[0][0][0];           // reuse as [16][512]
    {
      const unsigned short* pb = hpay + (size_t)g * PAYG + (size_t)tid * 32;
      s16x8 cc[4];
      cc[0] = ((const s16x8*)pb)[0];
      cc[1] = ((const s16x8*)pb)[1];
      cc[2] = ((const s16x8*)pb)[2];
      cc[3] = ((const s16x8*)pb)[3];
      const int kb = tid >> 4;
      const int L0 = (tid & 15) * 4;
#pragma unroll
      for (int i = 0; i < 4; ++i) {
        const int L = L0 + i;
        const int m = L & 15, qq = L >> 4;
        *(s16x8*)&hfc[m * 512 + kb * 32 + qq * 8] = cc[i];
      }
    }
    __syncthreads();

    if (tid < BC * 10) {
      const int row = tid / 10, o = tid - row * 10;
      const float* wr = fcw + (size_t)o * H_DIM;
      float sum = fcb[o];
      for (int k = 0; k < H_DIM; k += 8) {
#pragma unroll
        for (int j = 0; j < 8; ++j)
          sum += bf2f(hfc[row * 512 + k + j]) * wr[k + j];
      }
      out[(g * BC + row) * 10 + o] = sum;
    }
  }
}

extern "C" void kernel_launch(void* const* d_in, const int* in_sizes, int n_in,
                              void* d_out, int out_size, void* d_ws, size_t ws_size,
                              hipStream_t stream) {
  (void)in_sizes; (void)n_in; (void)out_size;
  const float* x   = (const float*)d_in[0];
  const float* Wih = (const float*)d_in[1];
  const float* Whh = (const float*)d_in[2];
  const float* bih = (const float*)d_in[3];
  const float* bhh = (const float*)d_in[4];
  const float* fcw = (const float*)d_in[5];
  const float* fcb = (const float*)d_in[6];

  int* arrive = (int*)d_ws;                          // @0
  int* table  = (int*)((char*)d_ws + 4096);          // @4K, 512 ints
  int* flags  = (int*)((char*)d_ws + 8192);          // @8K, [8][32][16] ints
  unsigned short* hpay = (unsigned short*)((char*)d_ws + 32768);

  // rotation depth W: power of two, 2..16 (16 => ~512 KB vL1 turnover per
  // address reuse -- the PROVEN plain-load freshness mechanism)
  size_t avail = ws_size > 32768 ? ws_size - 32768 : 0;
  int W = 2;
  while (W < 16 && (size_t)(W * 2) * (PAYSLOT * 2) <= avail) W <<= 1;

  // zero arrive + table + flag region (flags MUST start at 0;
  // re-zeroed every launch -> graph-replay safe)
  hipMemsetAsync(d_ws, 0, 32768, stream);

  hipLaunchKernelGGL(lstm_persistent, dim3(NBLK), dim3(256), 0, stream,
                     x, Wih, Whh, bih, bhh, fcw, fcb, (float*)d_out,
                     arrive, table, flags, hpay, W - 1);
}